// Round 1
// 907.226 us; speedup vs baseline: 1.1769x; 1.1769x over previous
//
#include <hip/hip_runtime.h>
#include <hip/hip_bf16.h>

typedef __attribute__((ext_vector_type(8))) short short8;
typedef __attribute__((ext_vector_type(4))) short short4v;
typedef __attribute__((ext_vector_type(4))) float floatx4;

#define D128 128

__device__ __forceinline__ short f2bf(float f) {
    union { float f; unsigned u; } x; x.f = f;
    unsigned r = x.u + 0x7FFFu + ((x.u >> 16) & 1u);
    return (short)(r >> 16);
}
__device__ __forceinline__ float bflo(unsigned u) { return __uint_as_float(u << 16); }
__device__ __forceinline__ float bfhi(unsigned u) { return __uint_as_float(u & 0xffff0000u); }

// ---- weight prep: per block, transpose one 128x128 fp32 W -> bf16 Wt[n][k] ----
// order: 0=Wq 1=Wk 2=Wv 3=Wskip 4=We 5=W1 6=W2
__global__ void wprep_kernel(const float* Wq, const float* Wk, const float* Wv,
                             const float* We, const float* Ws, const float* W1,
                             const float* W2, short* wt) {
    const float* src;
    switch (blockIdx.x) {
        case 0: src = Wq; break;
        case 1: src = Wk; break;
        case 2: src = Wv; break;
        case 3: src = Ws; break;
        case 4: src = We; break;
        case 5: src = W1; break;
        default: src = W2; break;
    }
    short* dst = wt + (size_t)blockIdx.x * D128 * D128;
    for (int i = threadIdx.x; i < D128 * D128; i += blockDim.x) {
        int k = i >> 7, n = i & 127;
        dst[n * D128 + k] = f2bf(src[i]);
    }
}

// ---- persistent GEMM: out[M x 128] = A[M x 128] @ W[128 x 128] (+bias) (+silu)
// W resident in LDS (loaded once per block); grid-stride over 64-row tiles;
// A fragments loaded straight from global into registers (no barriers in loop);
// swapped MFMA operands so each lane owns 4 consecutive output cols of its own
// row -> vectorized epilogue stores.
__device__ __forceinline__ void load_W(const short* __restrict__ Wt, short* Bs) {
    const short8* wp = (const short8*)Wt;
    const int tid = threadIdx.x;
#pragma unroll
    for (int it = 0; it < 8; ++it) {
        int i = it * 256 + tid;
        int n = i >> 4, kg = i & 15;
        *(short8*)(&Bs[n * 136 + kg * 8]) = wp[i];
    }
    __syncthreads();
}

template <typename TA, typename TO, int SILU>
__device__ __forceinline__ void gemm_core(const TA* __restrict__ A,
                                          const float* __restrict__ bias,
                                          TO* __restrict__ out, int M,
                                          const short* Bs) {
    const int tid = threadIdx.x;
    const int wv = tid >> 6, lane = tid & 63;
    const int m = lane & 15, quad = lane >> 4;
    const int ntiles = (M + 63) >> 6;

    for (int tile = blockIdx.x; tile < ntiles; tile += gridDim.x) {
        const int row = tile * 64 + wv * 16 + m;
        const bool valid = row < M;

        short8 af[4];
        if constexpr (sizeof(TA) == 4) {
            const float* ap = (const float*)A + (size_t)row * D128;
#pragma unroll
            for (int kk = 0; kk < 4; ++kk) {
                float4 u0 = make_float4(0.f, 0.f, 0.f, 0.f), u1 = u0;
                if (valid) {
                    u0 = *(const float4*)(ap + kk * 32 + quad * 8);
                    u1 = *(const float4*)(ap + kk * 32 + quad * 8 + 4);
                }
                short8 s;
                s[0] = f2bf(u0.x); s[1] = f2bf(u0.y); s[2] = f2bf(u0.z); s[3] = f2bf(u0.w);
                s[4] = f2bf(u1.x); s[5] = f2bf(u1.y); s[6] = f2bf(u1.z); s[7] = f2bf(u1.w);
                af[kk] = s;
            }
        } else {
            const short8* ap = (const short8*)((const short*)A + (size_t)row * D128);
#pragma unroll
            for (int kk = 0; kk < 4; ++kk) {
                short8 s;
#pragma unroll
                for (int j = 0; j < 8; ++j) s[j] = 0;
                if (valid) s = ap[kk * 4 + quad];
                af[kk] = s;
            }
        }

        floatx4 acc[8];
#pragma unroll
        for (int t = 0; t < 8; ++t) acc[t] = (floatx4){0.f, 0.f, 0.f, 0.f};

#pragma unroll
        for (int kk = 0; kk < 4; ++kk) {
            const int kq = kk * 32 + quad * 8;
#pragma unroll
            for (int t = 0; t < 8; ++t) {
                short8 bf = *(const short8*)(&Bs[(t * 16 + m) * 136 + kq]);
                // swapped operands: D'[i][j] = sum_k W[k][t*16+i] * A[rowtile+j][k]
                // lane holds out[row][t*16 + quad*4 + r] -> contiguous cols
                acc[t] = __builtin_amdgcn_mfma_f32_16x16x32_bf16(bf, af[kk], acc[t], 0, 0, 0);
            }
        }

        if (valid) {
            TO* op = out + (size_t)row * D128;
#pragma unroll
            for (int t = 0; t < 8; ++t) {
                const int c = t * 16 + quad * 4;
                float4 bv = make_float4(0.f, 0.f, 0.f, 0.f);
                if (bias) bv = *(const float4*)(bias + c);
                float v0 = acc[t][0] + bv.x;
                float v1 = acc[t][1] + bv.y;
                float v2 = acc[t][2] + bv.z;
                float v3 = acc[t][3] + bv.w;
                if (SILU) {
                    v0 = v0 / (1.f + __expf(-v0));
                    v1 = v1 / (1.f + __expf(-v1));
                    v2 = v2 / (1.f + __expf(-v2));
                    v3 = v3 / (1.f + __expf(-v3));
                }
                if constexpr (sizeof(TO) == 4) {
                    *(float4*)(op + c) = make_float4(v0, v1, v2, v3);
                } else {
                    short4v s;
                    s.x = f2bf(v0); s.y = f2bf(v1); s.z = f2bf(v2); s.w = f2bf(v3);
                    *(short4v*)(op + c) = s;
                }
            }
        }
    }
}

template <typename TA, typename TO, int SILU>
__global__ __launch_bounds__(256) void gemmP(const TA* __restrict__ A,
                                             const short* __restrict__ Wt,
                                             const float* __restrict__ bias,
                                             TO* __restrict__ out, int M) {
    __shared__ __attribute__((aligned(16))) short Bs[128 * 136];
    load_W(Wt, Bs);
    gemm_core<TA, TO, SILU>(A, bias, out, M, Bs);
}

// fused q/k/v/skip projections: blockIdx.y selects the weight/bias/output
__global__ __launch_bounds__(256) void gemm_qkvs(const float* __restrict__ x,
                                                 const short* __restrict__ wt,
                                                 const float* __restrict__ bq,
                                                 const float* __restrict__ bk,
                                                 const float* __restrict__ bv,
                                                 const float* __restrict__ bs,
                                                 short* __restrict__ q,
                                                 short* __restrict__ k,
                                                 short* __restrict__ v,
                                                 short* __restrict__ s, int M) {
    __shared__ __attribute__((aligned(16))) short Bs[128 * 136];
    const int y = blockIdx.y;
    load_W(wt + (size_t)y * 16384, Bs);
    const float* bias = (y == 0) ? bq : (y == 1) ? bk : (y == 2) ? bv : bs;
    short* out = (y == 0) ? q : (y == 1) ? k : (y == 2) ? v : s;
    gemm_core<float, short, 0>(x, bias, out, M, Bs);
}

// ---- CSR build ----
__global__ void hist_kernel(const int* __restrict__ ei, int* __restrict__ deg, int E) {
    int i = blockIdx.x * 256 + threadIdx.x;
    if (i < E) atomicAdd(&deg[ei[(size_t)E + i]], 1);
}

__global__ __launch_bounds__(256) void scan_a(const int* __restrict__ deg,
                                              int* __restrict__ rowstart,
                                              int* __restrict__ partials, int N) {
    __shared__ int lds[256];
    int base = blockIdx.x * 1024;
    int t = threadIdx.x;
    int v[4];
    int s = 0;
#pragma unroll
    for (int j = 0; j < 4; ++j) {
        int i = base + t * 4 + j;
        v[j] = (i < N) ? deg[i] : 0;
        s += v[j];
    }
    lds[t] = s;
    __syncthreads();
    int val = s;
    for (int off = 1; off < 256; off <<= 1) {
        int other = (t >= off) ? lds[t - off] : 0;
        __syncthreads();
        val += other;
        lds[t] = val;
        __syncthreads();
    }
    int excl = val - s;
#pragma unroll
    for (int j = 0; j < 4; ++j) {
        int i = base + t * 4 + j;
        if (i < N) rowstart[i] = excl;
        excl += v[j];
    }
    if (t == 255) partials[blockIdx.x] = val;
}

__global__ __launch_bounds__(256) void scan_b(int* __restrict__ partials, int n) {
    __shared__ int lds[256];
    int t = threadIdx.x;
    int s = (t < n) ? partials[t] : 0;
    lds[t] = s;
    __syncthreads();
    int val = s;
    for (int off = 1; off < 256; off <<= 1) {
        int other = (t >= off) ? lds[t - off] : 0;
        __syncthreads();
        val += other;
        lds[t] = val;
        __syncthreads();
    }
    if (t < n) partials[t] = val - s;
}

__global__ void scan_c(int* __restrict__ rowstart, const int* __restrict__ partials,
                       int N, int Etot) {
    int i = blockIdx.x * 256 + threadIdx.x;
    if (i < N) rowstart[i] += partials[i >> 10];
    if (i == 0) rowstart[N] = Etot;
}

__global__ void fill_kernel(const int* __restrict__ ei, int* __restrict__ cursor,
                            int2* __restrict__ cst, int E) {
    int i = blockIdx.x * 256 + threadIdx.x;
    if (i >= E) return;
    int src = ei[i], dst = ei[(size_t)E + i];
    int slot = atomicAdd(&cursor[dst], 1);
    cst[slot] = make_int2(src, i);
}

// ---- fused attention gather: per node, single pass over incoming edges ----
__global__ __launch_bounds__(256) void attn_gather(const int* __restrict__ rowstart,
                                                   const int2* __restrict__ cst,
                                                   const unsigned* __restrict__ q2,
                                                   const unsigned* __restrict__ k2,
                                                   const unsigned* __restrict__ v2,
                                                   const unsigned* __restrict__ e2,
                                                   float* __restrict__ attn, int N) {
    int t = threadIdx.x;
    int node = blockIdx.x * 4 + (t >> 6);
    if (node >= N) return;
    int l = t & 63;
    unsigned qu = q2[(size_t)node * 64 + l];
    float q0 = bflo(qu), q1 = bfhi(qu);
    int p0 = rowstart[node], p1 = rowstart[node + 1];
    float num0 = 0.f, num1 = 0.f, den = 0.f;
    for (int p = p0; p < p1; ++p) {
        int2 se = cst[p];
        unsigned ku = k2[(size_t)se.x * 64 + l];
        unsigned eu = e2[(size_t)se.y * 64 + l];
        unsigned vu = v2[(size_t)se.x * 64 + l];
        float ke0 = bflo(ku) + bflo(eu), ke1 = bfhi(ku) + bfhi(eu);
        float pd = q0 * ke0 + q1 * ke1;
        pd += __shfl_xor(pd, 1);
        pd += __shfl_xor(pd, 2);
        pd += __shfl_xor(pd, 4);
        float ex = __expf(pd * 0.25f);
        den += ex;
        num0 += ex * (bflo(vu) + bflo(eu));
        num1 += ex * (bfhi(vu) + bfhi(eu));
    }
    float inv = 1.f / (den + 1e-16f);
    float2 o;
    o.x = num0 * inv;
    o.y = num1 * inv;
    *(float2*)(attn + (size_t)node * D128 + l * 2) = o;
}

// ---- h = x + LN(attn + skip); one wave per row (skip is bf16) ----
__global__ __launch_bounds__(256) void ln_h_kernel(const float* __restrict__ attn,
                                                   const unsigned* __restrict__ skip2,
                                                   const float* __restrict__ x,
                                                   const float* __restrict__ g,
                                                   const float* __restrict__ b,
                                                   float* __restrict__ h, int N) {
    int t = threadIdx.x;
    int r = blockIdx.x * 4 + (t >> 6);
    if (r >= N) return;
    int l = t & 63;
    int c0 = l * 2;
    size_t base = (size_t)r * D128;
    float2 a = *(const float2*)(attn + base + c0);
    unsigned su = skip2[(size_t)r * 64 + l];
    float v0 = a.x + bflo(su), v1 = a.y + bfhi(su);
    float sum = v0 + v1;
#pragma unroll
    for (int o = 32; o > 0; o >>= 1) sum += __shfl_xor(sum, o);
    float mu = sum * (1.f / 128.f);
    float d0 = v0 - mu, d1 = v1 - mu;
    float vs = d0 * d0 + d1 * d1;
#pragma unroll
    for (int o = 32; o > 0; o >>= 1) vs += __shfl_xor(vs, o);
    float rs = rsqrtf(vs * (1.f / 128.f) + 1e-5f);
    float2 xe = *(const float2*)(x + base + c0);
    float2 o2;
    o2.x = xe.x + d0 * rs * g[c0] + b[c0];
    o2.y = xe.y + d1 * rs * g[c0 + 1] + b[c0 + 1];
    *(float2*)(h + base + c0) = o2;
}

// ---- out = h + LN(ffn); one wave per row ----
__global__ __launch_bounds__(256) void ln_out_kernel(const float* __restrict__ ffn,
                                                     const float* __restrict__ h,
                                                     const float* __restrict__ g,
                                                     const float* __restrict__ b,
                                                     float* __restrict__ out, int N) {
    int t = threadIdx.x;
    int r = blockIdx.x * 4 + (t >> 6);
    if (r >= N) return;
    int c0 = (t & 63) * 2;
    size_t base = (size_t)r * D128;
    float2 f = *(const float2*)(ffn + base + c0);
    float v0 = f.x, v1 = f.y;
    float sum = v0 + v1;
#pragma unroll
    for (int o = 32; o > 0; o >>= 1) sum += __shfl_xor(sum, o);
    float mu = sum * (1.f / 128.f);
    float d0 = v0 - mu, d1 = v1 - mu;
    float vs = d0 * d0 + d1 * d1;
#pragma unroll
    for (int o = 32; o > 0; o >>= 1) vs += __shfl_xor(vs, o);
    float rs = rsqrtf(vs * (1.f / 128.f) + 1e-5f);
    float2 he = *(const float2*)(h + base + c0);
    float2 o2;
    o2.x = he.x + d0 * rs * g[c0] + b[c0];
    o2.y = he.y + d1 * rs * g[c0 + 1] + b[c0 + 1];
    *(float2*)(out + base + c0) = o2;
}

extern "C" void kernel_launch(void* const* d_in, const int* in_sizes, int n_in,
                              void* d_out, int out_size, void* d_ws, size_t ws_size,
                              hipStream_t stream) {
    const int*   ei    = (const int*)d_in[0];
    const float* x     = (const float*)d_in[1];
    const float* ea    = (const float*)d_in[2];
    const float* Wq    = (const float*)d_in[3];
    const float* bq    = (const float*)d_in[4];
    const float* Wk    = (const float*)d_in[5];
    const float* bk    = (const float*)d_in[6];
    const float* Wv    = (const float*)d_in[7];
    const float* bv    = (const float*)d_in[8];
    const float* We    = (const float*)d_in[9];
    const float* Wsk   = (const float*)d_in[10];
    const float* bskip = (const float*)d_in[11];
    const float* W1    = (const float*)d_in[12];
    const float* b1    = (const float*)d_in[13];
    const float* W2    = (const float*)d_in[14];
    const float* b2    = (const float*)d_in[15];
    const float* g1    = (const float*)d_in[16];
    const float* be1   = (const float*)d_in[17];
    const float* g2    = (const float*)d_in[18];
    const float* be2   = (const float*)d_in[19];

    const int N = in_sizes[1] / D128;
    const int E = in_sizes[2] / D128;
    const size_t nd = (size_t)N * D128;
    const size_t ed = (size_t)E * D128;

    char* p = (char*)d_ws;
    auto alloc = [&](size_t bytes) {
        char* r = p;
        p += (bytes + 255) & ~(size_t)255;
        return (void*)r;
    };
    short* qb       = (short*)alloc(nd * 2);
    short* kb       = (short*)alloc(nd * 2);
    short* vb       = (short*)alloc(nd * 2);
    short* sb       = (short*)alloc(nd * 2);   // skip
    short* ebuf     = (short*)alloc(ed * 2);
    float* attn     = (float*)alloc(nd * 4);
    float* h        = (float*)alloc(nd * 4);
    short* t1b      = (short*)alloc(nd * 2);
    float* ffn      = (float*)alloc(nd * 4);
    short* wt       = (short*)alloc(7 * 16384 * 2);
    int*   deg      = (int*)alloc((size_t)N * 4);
    int*   rowstart = (int*)alloc(((size_t)N + 1) * 4);
    int*   partials = (int*)alloc(512 * 4);
    int*   cursor   = (int*)alloc((size_t)N * 4);
    int2*  cst      = (int2*)alloc((size_t)E * 8);

    const int tilesN = (N + 63) / 64;
    const int tilesE = (E + 63) / 64;
    const int gxN = tilesN < 1024 ? tilesN : 1024;
    const int gxE = tilesE < 1024 ? tilesE : 1024;
    const int gxQ = tilesN < 512 ? tilesN : 512;
    const int nchunks = (N + 1023) / 1024;

    wprep_kernel<<<7, 256, 0, stream>>>(Wq, Wk, Wv, We, Wsk, W1, W2, wt);

    // CSR build (by dst)
    hipMemsetAsync(deg, 0, (size_t)N * 4, stream);
    hist_kernel<<<(E + 255) / 256, 256, 0, stream>>>(ei, deg, E);
    scan_a<<<nchunks, 256, 0, stream>>>(deg, rowstart, partials, N);
    scan_b<<<1, 256, 0, stream>>>(partials, nchunks);
    scan_c<<<(N + 255) / 256, 256, 0, stream>>>(rowstart, partials, N, E);
    hipMemcpyAsync(cursor, rowstart, (size_t)N * 4, hipMemcpyDeviceToDevice, stream);
    fill_kernel<<<(E + 255) / 256, 256, 0, stream>>>(ei, cursor, cst, E);

    // projections (bf16 outputs): fused q/k/v/skip + edge projection
    gemm_qkvs<<<dim3(gxQ, 4), 256, 0, stream>>>(x, wt, bq, bk, bv, bskip,
                                                qb, kb, vb, sb, N);
    gemmP<float, short, 0><<<gxE, 256, 0, stream>>>(ea, wt + 4 * 16384, nullptr, ebuf, E);

    // fused attention (atomic-free gather)
    attn_gather<<<(N + 3) / 4, 256, 0, stream>>>(rowstart, cst, (const unsigned*)qb,
                                                 (const unsigned*)kb, (const unsigned*)vb,
                                                 (const unsigned*)ebuf, attn, N);

    ln_h_kernel<<<(N + 3) / 4, 256, 0, stream>>>(attn, (const unsigned*)sb, x, g1, be1, h, N);
    gemmP<float, short, 1><<<gxN, 256, 0, stream>>>(h, wt + 5 * 16384, b1, t1b, N);
    gemmP<short, float, 0><<<gxN, 256, 0, stream>>>(t1b, wt + 6 * 16384, b2, ffn, N);
    ln_out_kernel<<<(N + 3) / 4, 256, 0, stream>>>(ffn, h, g2, be2, (float*)d_out, N);
}

// Round 2
// 838.976 us; speedup vs baseline: 1.2726x; 1.0813x over previous
//
#include <hip/hip_runtime.h>
#include <hip/hip_bf16.h>

typedef __attribute__((ext_vector_type(8))) short short8;
typedef __attribute__((ext_vector_type(4))) short short4v;
typedef __attribute__((ext_vector_type(4))) float floatx4;

#define D128 128

__device__ __forceinline__ short f2bf(float f) {
    union { float f; unsigned u; } x; x.f = f;
    unsigned r = x.u + 0x7FFFu + ((x.u >> 16) & 1u);
    return (short)(r >> 16);
}
__device__ __forceinline__ float bflo(unsigned u) { return __uint_as_float(u << 16); }
__device__ __forceinline__ float bfhi(unsigned u) { return __uint_as_float(u & 0xffff0000u); }

// ---- weight prep: per block, transpose one 128x128 fp32 W -> bf16 Wt[n][k] ----
// order: 0=Wq 1=Wk 2=Wv 3=Wskip 4=We 5=W1 6=W2
__global__ void wprep_kernel(const float* Wq, const float* Wk, const float* Wv,
                             const float* We, const float* Ws, const float* W1,
                             const float* W2, short* wt) {
    const float* src;
    switch (blockIdx.x) {
        case 0: src = Wq; break;
        case 1: src = Wk; break;
        case 2: src = Wv; break;
        case 3: src = Ws; break;
        case 4: src = We; break;
        case 5: src = W1; break;
        default: src = W2; break;
    }
    short* dst = wt + (size_t)blockIdx.x * D128 * D128;
    for (int i = threadIdx.x; i < D128 * D128; i += blockDim.x) {
        int k = i >> 7, n = i & 127;
        dst[n * D128 + k] = f2bf(src[i]);
    }
}

// ---- persistent GEMM pieces ----
__device__ __forceinline__ void load_W(const short* __restrict__ Wt, short* Bs) {
    const short8* wp = (const short8*)Wt;
    const int tid = threadIdx.x;
#pragma unroll
    for (int it = 0; it < 8; ++it) {
        int i = it * 256 + tid;
        int n = i >> 4, kg = i & 15;
        *(short8*)(&Bs[n * 136 + kg * 8]) = wp[i];
    }
    __syncthreads();
}

// out[M x 128] = A[M x 128] @ W (+bias) (+silu); optional rowmap scatters output rows.
template <typename TA, typename TO, int SILU>
__device__ __forceinline__ void gemm_core(const TA* __restrict__ A,
                                          const float* __restrict__ bias,
                                          TO* __restrict__ out, int M,
                                          const short* Bs,
                                          const int* __restrict__ rowmap) {
    const int tid = threadIdx.x;
    const int wv = tid >> 6, lane = tid & 63;
    const int m = lane & 15, quad = lane >> 4;
    const int ntiles = (M + 63) >> 6;

    for (int tile = blockIdx.x; tile < ntiles; tile += gridDim.x) {
        const int row = tile * 64 + wv * 16 + m;
        const bool valid = row < M;

        short8 af[4];
        if constexpr (sizeof(TA) == 4) {
            const float* ap = (const float*)A + (size_t)row * D128;
#pragma unroll
            for (int kk = 0; kk < 4; ++kk) {
                float4 u0 = make_float4(0.f, 0.f, 0.f, 0.f), u1 = u0;
                if (valid) {
                    u0 = *(const float4*)(ap + kk * 32 + quad * 8);
                    u1 = *(const float4*)(ap + kk * 32 + quad * 8 + 4);
                }
                short8 s;
                s[0] = f2bf(u0.x); s[1] = f2bf(u0.y); s[2] = f2bf(u0.z); s[3] = f2bf(u0.w);
                s[4] = f2bf(u1.x); s[5] = f2bf(u1.y); s[6] = f2bf(u1.z); s[7] = f2bf(u1.w);
                af[kk] = s;
            }
        } else {
            const short8* ap = (const short8*)((const short*)A + (size_t)row * D128);
#pragma unroll
            for (int kk = 0; kk < 4; ++kk) {
                short8 s;
#pragma unroll
                for (int j = 0; j < 8; ++j) s[j] = 0;
                if (valid) s = ap[kk * 4 + quad];
                af[kk] = s;
            }
        }

        floatx4 acc[8];
#pragma unroll
        for (int t = 0; t < 8; ++t) acc[t] = (floatx4){0.f, 0.f, 0.f, 0.f};

#pragma unroll
        for (int kk = 0; kk < 4; ++kk) {
            const int kq = kk * 32 + quad * 8;
#pragma unroll
            for (int t = 0; t < 8; ++t) {
                short8 bf = *(const short8*)(&Bs[(t * 16 + m) * 136 + kq]);
                acc[t] = __builtin_amdgcn_mfma_f32_16x16x32_bf16(bf, af[kk], acc[t], 0, 0, 0);
            }
        }

        if (valid) {
            size_t orow = rowmap ? (size_t)rowmap[row] : (size_t)row;
            TO* op = out + orow * D128;
#pragma unroll
            for (int t = 0; t < 8; ++t) {
                const int c = t * 16 + quad * 4;
                floatx4 bv = (floatx4){0.f, 0.f, 0.f, 0.f};
                if (bias) bv = *(const floatx4*)(bias + c);
                float v0 = acc[t][0] + bv[0];
                float v1 = acc[t][1] + bv[1];
                float v2 = acc[t][2] + bv[2];
                float v3 = acc[t][3] + bv[3];
                if (SILU) {
                    v0 = v0 / (1.f + __expf(-v0));
                    v1 = v1 / (1.f + __expf(-v1));
                    v2 = v2 / (1.f + __expf(-v2));
                    v3 = v3 / (1.f + __expf(-v3));
                }
                if constexpr (sizeof(TO) == 4) {
                    *(floatx4*)(op + c) = (floatx4){v0, v1, v2, v3};
                } else {
                    short4v s;
                    s.x = f2bf(v0); s.y = f2bf(v1); s.z = f2bf(v2); s.w = f2bf(v3);
                    *(short4v*)(op + c) = s;
                }
            }
        }
    }
}

template <typename TA, typename TO, int SILU>
__global__ __launch_bounds__(256) void gemmP(const TA* __restrict__ A,
                                             const short* __restrict__ Wt,
                                             const float* __restrict__ bias,
                                             TO* __restrict__ out, int M,
                                             const int* __restrict__ rowmap) {
    __shared__ __attribute__((aligned(16))) short Bs[128 * 136];
    load_W(Wt, Bs);
    gemm_core<TA, TO, SILU>(A, bias, out, M, Bs, rowmap);
}

// fused q/k/v/skip projections: blockIdx.y selects the weight/bias/output
__global__ __launch_bounds__(256) void gemm_qkvs(const float* __restrict__ x,
                                                 const short* __restrict__ wt,
                                                 const float* __restrict__ bq,
                                                 const float* __restrict__ bk,
                                                 const float* __restrict__ bv,
                                                 const float* __restrict__ bs,
                                                 short* __restrict__ q,
                                                 short* __restrict__ k,
                                                 short* __restrict__ v,
                                                 short* __restrict__ s, int M) {
    __shared__ __attribute__((aligned(16))) short Bs[128 * 136];
    const int y = blockIdx.y;
    load_W(wt + (size_t)y * 16384, Bs);
    const float* bias = (y == 0) ? bq : (y == 1) ? bk : (y == 2) ? bv : bs;
    short* out = (y == 0) ? q : (y == 1) ? k : (y == 2) ? v : s;
    gemm_core<float, short, 0>(x, bias, out, M, Bs, nullptr);
}

// ---- FFN2 GEMM fused with out = h + LN(ffn) epilogue ----
// Row r is owned by lanes {m, m+16, m+32, m+48}; row stats via shfl_xor(16,32).
__global__ __launch_bounds__(256) void gemm_ln_out(const short* __restrict__ A,
                                                   const short* __restrict__ Wt,
                                                   const float* __restrict__ bias,
                                                   const float* __restrict__ h,
                                                   const float* __restrict__ g,
                                                   const float* __restrict__ b,
                                                   float* __restrict__ out, int M) {
    __shared__ __attribute__((aligned(16))) short Bs[128 * 136];
    load_W(Wt, Bs);
    const int tid = threadIdx.x;
    const int wv = tid >> 6, lane = tid & 63;
    const int m = lane & 15, quad = lane >> 4;
    const int ntiles = (M + 63) >> 6;

    for (int tile = blockIdx.x; tile < ntiles; tile += gridDim.x) {
        const int row = tile * 64 + wv * 16 + m;
        const bool valid = row < M;

        short8 af[4];
        const short8* ap = (const short8*)(A + (size_t)row * D128);
#pragma unroll
        for (int kk = 0; kk < 4; ++kk) {
            short8 s;
#pragma unroll
            for (int j = 0; j < 8; ++j) s[j] = 0;
            if (valid) s = ap[kk * 4 + quad];
            af[kk] = s;
        }

        floatx4 acc[8];
#pragma unroll
        for (int t = 0; t < 8; ++t) acc[t] = (floatx4){0.f, 0.f, 0.f, 0.f};

#pragma unroll
        for (int kk = 0; kk < 4; ++kk) {
            const int kq = kk * 32 + quad * 8;
#pragma unroll
            for (int t = 0; t < 8; ++t) {
                short8 bf = *(const short8*)(&Bs[(t * 16 + m) * 136 + kq]);
                acc[t] = __builtin_amdgcn_mfma_f32_16x16x32_bf16(bf, af[kk], acc[t], 0, 0, 0);
            }
        }

        // LN epilogue over the 128-wide row (spread across 4 quad-lanes)
        float vals[8][4];
        float sum = 0.f;
#pragma unroll
        for (int t = 0; t < 8; ++t) {
            const int c = t * 16 + quad * 4;
            floatx4 bv = *(const floatx4*)(bias + c);
#pragma unroll
            for (int r = 0; r < 4; ++r) {
                float v = acc[t][r] + bv[r];
                vals[t][r] = v;
                sum += v;
            }
        }
        sum += __shfl_xor(sum, 16);
        sum += __shfl_xor(sum, 32);
        float mu = sum * (1.f / 128.f);
        float vs = 0.f;
#pragma unroll
        for (int t = 0; t < 8; ++t)
#pragma unroll
            for (int r = 0; r < 4; ++r) {
                float d = vals[t][r] - mu;
                vals[t][r] = d;
                vs += d * d;
            }
        vs += __shfl_xor(vs, 16);
        vs += __shfl_xor(vs, 32);
        float rs = rsqrtf(vs * (1.f / 128.f) + 1e-5f);

        if (valid) {
            const float* hp = h + (size_t)row * D128;
            float* op = out + (size_t)row * D128;
#pragma unroll
            for (int t = 0; t < 8; ++t) {
                const int c = t * 16 + quad * 4;
                floatx4 hv = *(const floatx4*)(hp + c);
                floatx4 gv = *(const floatx4*)(g + c);
                floatx4 bb = *(const floatx4*)(b + c);
                floatx4 o;
#pragma unroll
                for (int r = 0; r < 4; ++r) o[r] = hv[r] + vals[t][r] * rs * gv[r] + bb[r];
                *(floatx4*)(op + c) = o;
            }
        }
    }
}

// ---- CSR build ----
__global__ void hist_kernel(const int* __restrict__ ei, int* __restrict__ deg, int E) {
    int i = blockIdx.x * 256 + threadIdx.x;
    if (i < E) atomicAdd(&deg[ei[(size_t)E + i]], 1);
}

__global__ __launch_bounds__(256) void scan_a(const int* __restrict__ deg,
                                              int* __restrict__ rowstart,
                                              int* __restrict__ partials, int N) {
    __shared__ int lds[256];
    int base = blockIdx.x * 1024;
    int t = threadIdx.x;
    int v[4];
    int s = 0;
#pragma unroll
    for (int j = 0; j < 4; ++j) {
        int i = base + t * 4 + j;
        v[j] = (i < N) ? deg[i] : 0;
        s += v[j];
    }
    lds[t] = s;
    __syncthreads();
    int val = s;
    for (int off = 1; off < 256; off <<= 1) {
        int other = (t >= off) ? lds[t - off] : 0;
        __syncthreads();
        val += other;
        lds[t] = val;
        __syncthreads();
    }
    int excl = val - s;
#pragma unroll
    for (int j = 0; j < 4; ++j) {
        int i = base + t * 4 + j;
        if (i < N) rowstart[i] = excl;
        excl += v[j];
    }
    if (t == 255) partials[blockIdx.x] = val;
}

__global__ __launch_bounds__(256) void scan_b(int* __restrict__ partials, int n) {
    __shared__ int lds[256];
    int t = threadIdx.x;
    int s = (t < n) ? partials[t] : 0;
    lds[t] = s;
    __syncthreads();
    int val = s;
    for (int off = 1; off < 256; off <<= 1) {
        int other = (t >= off) ? lds[t - off] : 0;
        __syncthreads();
        val += other;
        lds[t] = val;
        __syncthreads();
    }
    if (t < n) partials[t] = val - s;
}

// also seeds cursor (drops a D2D memcpy)
__global__ void scan_c(int* __restrict__ rowstart, const int* __restrict__ partials,
                       int* __restrict__ cursor, int N, int Etot) {
    int i = blockIdx.x * 256 + threadIdx.x;
    if (i < N) {
        int v = rowstart[i] + partials[i >> 10];
        rowstart[i] = v;
        cursor[i] = v;
    }
    if (i == 0) rowstart[N] = Etot;
}

// builds csrc[slot]=src and pos[edge]=slot (for CSR-ordered e projection)
__global__ void fill_kernel(const int* __restrict__ ei, int* __restrict__ cursor,
                            int* __restrict__ csrc, int* __restrict__ pos, int E) {
    int i = blockIdx.x * 256 + threadIdx.x;
    if (i >= E) return;
    int src = ei[i], dst = ei[(size_t)E + i];
    int slot = atomicAdd(&cursor[dst], 1);
    csrc[slot] = src;
    pos[i] = slot;
}

// ---- fused attention gather + (h = x + LN(attn + skip)) ----
// e is pre-permuted to CSR order -> sequential reads; 2-way unroll for MLP.
__global__ __launch_bounds__(256) void attn_ln_h(const int* __restrict__ rowstart,
                                                 const int* __restrict__ csrc,
                                                 const unsigned* __restrict__ q2,
                                                 const unsigned* __restrict__ k2,
                                                 const unsigned* __restrict__ v2,
                                                 const unsigned* __restrict__ ep2,
                                                 const unsigned* __restrict__ skip2,
                                                 const float* __restrict__ x,
                                                 const float* __restrict__ g,
                                                 const float* __restrict__ b,
                                                 float* __restrict__ h, int N) {
    int t = threadIdx.x;
    int node = blockIdx.x * 4 + (t >> 6);
    if (node >= N) return;
    int l = t & 63;
    unsigned qu = q2[(size_t)node * 64 + l];
    float q0 = bflo(qu), q1 = bfhi(qu);
    int p0 = rowstart[node], p1 = rowstart[node + 1];
    float num0 = 0.f, num1 = 0.f, den = 0.f;
    int p = p0;
    for (; p + 1 < p1; p += 2) {
        int s0 = csrc[p], s1 = csrc[p + 1];
        unsigned ku0 = k2[(size_t)s0 * 64 + l];
        unsigned ku1 = k2[(size_t)s1 * 64 + l];
        unsigned eu0 = ep2[(size_t)p * 64 + l];
        unsigned eu1 = ep2[(size_t)(p + 1) * 64 + l];
        unsigned vu0 = v2[(size_t)s0 * 64 + l];
        unsigned vu1 = v2[(size_t)s1 * 64 + l];
        float ka0 = bflo(ku0) + bflo(eu0), kb0 = bfhi(ku0) + bfhi(eu0);
        float pd0 = q0 * ka0 + q1 * kb0;
        float ka1 = bflo(ku1) + bflo(eu1), kb1 = bfhi(ku1) + bfhi(eu1);
        float pd1 = q0 * ka1 + q1 * kb1;
        pd0 += __shfl_xor(pd0, 1); pd1 += __shfl_xor(pd1, 1);
        pd0 += __shfl_xor(pd0, 2); pd1 += __shfl_xor(pd1, 2);
        pd0 += __shfl_xor(pd0, 4); pd1 += __shfl_xor(pd1, 4);
        float ex0 = __expf(pd0 * 0.25f);
        float ex1 = __expf(pd1 * 0.25f);
        den += ex0 + ex1;
        num0 += ex0 * (bflo(vu0) + bflo(eu0)) + ex1 * (bflo(vu1) + bflo(eu1));
        num1 += ex0 * (bfhi(vu0) + bfhi(eu0)) + ex1 * (bfhi(vu1) + bfhi(eu1));
    }
    if (p < p1) {
        int s0 = csrc[p];
        unsigned ku = k2[(size_t)s0 * 64 + l];
        unsigned eu = ep2[(size_t)p * 64 + l];
        unsigned vu = v2[(size_t)s0 * 64 + l];
        float ka = bflo(ku) + bflo(eu), kb = bfhi(ku) + bfhi(eu);
        float pd = q0 * ka + q1 * kb;
        pd += __shfl_xor(pd, 1);
        pd += __shfl_xor(pd, 2);
        pd += __shfl_xor(pd, 4);
        float ex = __expf(pd * 0.25f);
        den += ex;
        num0 += ex * (bflo(vu) + bflo(eu));
        num1 += ex * (bfhi(vu) + bfhi(eu));
    }
    float inv = 1.f / (den + 1e-16f);
    float v0 = num0 * inv, v1 = num1 * inv;

    // h = x + LN(attnrow + skip)
    unsigned su = skip2[(size_t)node * 64 + l];
    v0 += bflo(su); v1 += bfhi(su);
    float sum = v0 + v1;
#pragma unroll
    for (int o = 32; o > 0; o >>= 1) sum += __shfl_xor(sum, o);
    float mu = sum * (1.f / 128.f);
    float d0 = v0 - mu, d1 = v1 - mu;
    float vs = d0 * d0 + d1 * d1;
#pragma unroll
    for (int o = 32; o > 0; o >>= 1) vs += __shfl_xor(vs, o);
    float rs = rsqrtf(vs * (1.f / 128.f) + 1e-5f);
    int c0 = l * 2;
    size_t base = (size_t)node * D128;
    float2 xe = *(const float2*)(x + base + c0);
    float2 o2;
    o2.x = xe.x + d0 * rs * g[c0] + b[c0];
    o2.y = xe.y + d1 * rs * g[c0 + 1] + b[c0 + 1];
    *(float2*)(h + base + c0) = o2;
}

extern "C" void kernel_launch(void* const* d_in, const int* in_sizes, int n_in,
                              void* d_out, int out_size, void* d_ws, size_t ws_size,
                              hipStream_t stream) {
    const int*   ei    = (const int*)d_in[0];
    const float* x     = (const float*)d_in[1];
    const float* ea    = (const float*)d_in[2];
    const float* Wq    = (const float*)d_in[3];
    const float* bq    = (const float*)d_in[4];
    const float* Wk    = (const float*)d_in[5];
    const float* bk    = (const float*)d_in[6];
    const float* Wv    = (const float*)d_in[7];
    const float* bv    = (const float*)d_in[8];
    const float* We    = (const float*)d_in[9];
    const float* Wsk   = (const float*)d_in[10];
    const float* bskip = (const float*)d_in[11];
    const float* W1    = (const float*)d_in[12];
    const float* b1    = (const float*)d_in[13];
    const float* W2    = (const float*)d_in[14];
    const float* b2    = (const float*)d_in[15];
    const float* g1    = (const float*)d_in[16];
    const float* be1   = (const float*)d_in[17];
    const float* g2    = (const float*)d_in[18];
    const float* be2   = (const float*)d_in[19];

    const int N = in_sizes[1] / D128;
    const int E = in_sizes[2] / D128;
    const size_t nd = (size_t)N * D128;
    const size_t ed = (size_t)E * D128;

    char* p = (char*)d_ws;
    auto alloc = [&](size_t bytes) {
        char* r = p;
        p += (bytes + 255) & ~(size_t)255;
        return (void*)r;
    };
    short* qb       = (short*)alloc(nd * 2);
    short* kb       = (short*)alloc(nd * 2);
    short* vb       = (short*)alloc(nd * 2);
    short* sb       = (short*)alloc(nd * 2);   // skip
    short* ebuf     = (short*)alloc(ed * 2);   // CSR-permuted e projection
    float* h        = (float*)alloc(nd * 4);
    short* t1b      = (short*)alloc(nd * 2);
    short* wt       = (short*)alloc(7 * 16384 * 2);
    int*   deg      = (int*)alloc((size_t)N * 4);
    int*   rowstart = (int*)alloc(((size_t)N + 1) * 4);
    int*   partials = (int*)alloc(512 * 4);
    int*   cursor   = (int*)alloc((size_t)N * 4);
    int*   csrc     = (int*)alloc((size_t)E * 4);
    int*   pos      = (int*)alloc((size_t)E * 4);

    const int tilesN = (N + 63) / 64;
    const int tilesE = (E + 63) / 64;
    const int gxN = tilesN < 1024 ? tilesN : 1024;
    const int gxE = tilesE < 1024 ? tilesE : 1024;
    const int gxQ = tilesN < 512 ? tilesN : 512;
    const int nchunks = (N + 1023) / 1024;

    wprep_kernel<<<7, 256, 0, stream>>>(Wq, Wk, Wv, We, Wsk, W1, W2, wt);

    // CSR build (by dst)
    hipMemsetAsync(deg, 0, (size_t)N * 4, stream);
    hist_kernel<<<(E + 255) / 256, 256, 0, stream>>>(ei, deg, E);
    scan_a<<<nchunks, 256, 0, stream>>>(deg, rowstart, partials, N);
    scan_b<<<1, 256, 0, stream>>>(partials, nchunks);
    scan_c<<<(N + 255) / 256, 256, 0, stream>>>(rowstart, partials, cursor, N, E);
    fill_kernel<<<(E + 255) / 256, 256, 0, stream>>>(ei, cursor, csrc, pos, E);

    // projections (bf16 outputs): fused q/k/v/skip; edge projection scattered to CSR order
    gemm_qkvs<<<dim3(gxQ, 4), 256, 0, stream>>>(x, wt, bq, bk, bv, bskip,
                                                qb, kb, vb, sb, N);
    gemmP<float, short, 0><<<gxE, 256, 0, stream>>>(ea, wt + 4 * 16384, nullptr, ebuf, E, pos);

    // fused attention gather + LN-h (atomic-free)
    attn_ln_h<<<(N + 3) / 4, 256, 0, stream>>>(rowstart, csrc, (const unsigned*)qb,
                                               (const unsigned*)kb, (const unsigned*)vb,
                                               (const unsigned*)ebuf, (const unsigned*)sb,
                                               x, g1, be1, h, N);

    // FFN: silu GEMM -> bf16, then FFN2 GEMM fused with out = h + LN(ffn)
    gemmP<float, short, 1><<<gxN, 256, 0, stream>>>(h, wt + 5 * 16384, b1, t1b, N, nullptr);
    gemm_ln_out<<<gxN, 256, 0, stream>>>(t1b, wt + 6 * 16384, b2, h, g2, be2,
                                         (float*)d_out, N);
}

// Round 3
// 803.976 us; speedup vs baseline: 1.3280x; 1.0435x over previous
//
#include <hip/hip_runtime.h>
#include <hip/hip_bf16.h>

typedef __attribute__((ext_vector_type(8))) short short8;
typedef __attribute__((ext_vector_type(4))) short short4v;
typedef __attribute__((ext_vector_type(4))) float floatx4;

#define D128 128

__device__ __forceinline__ short f2bf(float f) {
    union { float f; unsigned u; } x; x.f = f;
    unsigned r = x.u + 0x7FFFu + ((x.u >> 16) & 1u);
    return (short)(r >> 16);
}
__device__ __forceinline__ float bflo(unsigned u) { return __uint_as_float(u << 16); }
__device__ __forceinline__ float bfhi(unsigned u) { return __uint_as_float(u & 0xffff0000u); }

// ---- weight prep: per block, transpose one 128x128 fp32 W -> bf16 Wt[n][k] ----
// order: 0=Wq 1=Wk 2=Wv 3=Wskip 4=We 5=W1 6=W2
__global__ void wprep_kernel(const float* Wq, const float* Wk, const float* Wv,
                             const float* We, const float* Ws, const float* W1,
                             const float* W2, short* wt) {
    const float* src;
    switch (blockIdx.x) {
        case 0: src = Wq; break;
        case 1: src = Wk; break;
        case 2: src = Wv; break;
        case 3: src = Ws; break;
        case 4: src = We; break;
        case 5: src = W1; break;
        default: src = W2; break;
    }
    short* dst = wt + (size_t)blockIdx.x * D128 * D128;
    for (int i = threadIdx.x; i < D128 * D128; i += blockDim.x) {
        int k = i >> 7, n = i & 127;
        dst[n * D128 + k] = f2bf(src[i]);
    }
}

// ---- persistent GEMM pieces ----
__device__ __forceinline__ void load_W(const short* __restrict__ Wt, short* Bs) {
    const short8* wp = (const short8*)Wt;
    const int tid = threadIdx.x;
#pragma unroll
    for (int it = 0; it < 8; ++it) {
        int i = it * 256 + tid;
        int n = i >> 4, kg = i & 15;
        *(short8*)(&Bs[n * 136 + kg * 8]) = wp[i];
    }
    __syncthreads();
}

// out[M x 128] = A[M x 128] @ W (+bias) (+silu); optional rowmap scatters output rows.
// Tiles walked as tile = b0, b0+bstep, ...
template <typename TA, typename TO, int SILU>
__device__ __forceinline__ void gemm_core(const TA* __restrict__ A,
                                          const float* __restrict__ bias,
                                          TO* __restrict__ out, int M,
                                          const short* Bs,
                                          const int* __restrict__ rowmap,
                                          int b0, int bstep) {
    const int tid = threadIdx.x;
    const int wv = tid >> 6, lane = tid & 63;
    const int m = lane & 15, quad = lane >> 4;
    const int ntiles = (M + 63) >> 6;

    for (int tile = b0; tile < ntiles; tile += bstep) {
        const int row = tile * 64 + wv * 16 + m;
        const bool valid = row < M;

        short8 af[4];
        if constexpr (sizeof(TA) == 4) {
            const float* ap = (const float*)A + (size_t)row * D128;
#pragma unroll
            for (int kk = 0; kk < 4; ++kk) {
                float4 u0 = make_float4(0.f, 0.f, 0.f, 0.f), u1 = u0;
                if (valid) {
                    u0 = *(const float4*)(ap + kk * 32 + quad * 8);
                    u1 = *(const float4*)(ap + kk * 32 + quad * 8 + 4);
                }
                short8 s;
                s[0] = f2bf(u0.x); s[1] = f2bf(u0.y); s[2] = f2bf(u0.z); s[3] = f2bf(u0.w);
                s[4] = f2bf(u1.x); s[5] = f2bf(u1.y); s[6] = f2bf(u1.z); s[7] = f2bf(u1.w);
                af[kk] = s;
            }
        } else {
            const short8* ap = (const short8*)((const short*)A + (size_t)row * D128);
#pragma unroll
            for (int kk = 0; kk < 4; ++kk) {
                short8 s;
#pragma unroll
                for (int j = 0; j < 8; ++j) s[j] = 0;
                if (valid) s = ap[kk * 4 + quad];
                af[kk] = s;
            }
        }

        floatx4 acc[8];
#pragma unroll
        for (int t = 0; t < 8; ++t) acc[t] = (floatx4){0.f, 0.f, 0.f, 0.f};

#pragma unroll
        for (int kk = 0; kk < 4; ++kk) {
            const int kq = kk * 32 + quad * 8;
#pragma unroll
            for (int t = 0; t < 8; ++t) {
                short8 bf = *(const short8*)(&Bs[(t * 16 + m) * 136 + kq]);
                acc[t] = __builtin_amdgcn_mfma_f32_16x16x32_bf16(bf, af[kk], acc[t], 0, 0, 0);
            }
        }

        if (valid) {
            size_t orow = rowmap ? (size_t)rowmap[row] : (size_t)row;
            TO* op = out + orow * D128;
#pragma unroll
            for (int t = 0; t < 8; ++t) {
                const int c = t * 16 + quad * 4;
                floatx4 bv = (floatx4){0.f, 0.f, 0.f, 0.f};
                if (bias) bv = *(const floatx4*)(bias + c);
                float v0 = acc[t][0] + bv[0];
                float v1 = acc[t][1] + bv[1];
                float v2 = acc[t][2] + bv[2];
                float v3 = acc[t][3] + bv[3];
                if (SILU) {
                    v0 = v0 / (1.f + __expf(-v0));
                    v1 = v1 / (1.f + __expf(-v1));
                    v2 = v2 / (1.f + __expf(-v2));
                    v3 = v3 / (1.f + __expf(-v3));
                }
                if constexpr (sizeof(TO) == 4) {
                    *(floatx4*)(op + c) = (floatx4){v0, v1, v2, v3};
                } else {
                    short4v s;
                    s.x = f2bf(v0); s.y = f2bf(v1); s.z = f2bf(v2); s.w = f2bf(v3);
                    *(short4v*)(op + c) = s;
                }
            }
        }
    }
}

// ---- all 5 projections in one dispatch ----
// blocks [0,nbE): edge proj (We, scattered to CSR order via pos)
// blocks [nbE + y*nbQ, nbE + (y+1)*nbQ): q/k/v/skip slice y
__global__ __launch_bounds__(256) void proj_all(const float* __restrict__ x,
                                                const float* __restrict__ ea,
                                                const short* __restrict__ wt,
                                                const float* __restrict__ bq,
                                                const float* __restrict__ bk,
                                                const float* __restrict__ bvv,
                                                const float* __restrict__ bs,
                                                short* __restrict__ q,
                                                short* __restrict__ k,
                                                short* __restrict__ v,
                                                short* __restrict__ s,
                                                short* __restrict__ eb,
                                                const int* __restrict__ pos,
                                                int N, int E, int nbE, int nbQ) {
    __shared__ __attribute__((aligned(16))) short Bs[128 * 136];
    const int b = blockIdx.x;
    if (b < nbE) {
        load_W(wt + 4 * 16384, Bs);
        gemm_core<float, short, 0>(ea, nullptr, eb, E, Bs, pos, b, nbE);
    } else {
        const int y = (b - nbE) / nbQ, b2 = (b - nbE) % nbQ;
        load_W(wt + (size_t)y * 16384, Bs);
        const float* bias = (y == 0) ? bq : (y == 1) ? bk : (y == 2) ? bvv : bs;
        short* o = (y == 0) ? q : (y == 1) ? k : (y == 2) ? v : s;
        gemm_core<float, short, 0>(x, bias, o, N, Bs, nullptr, b2, nbQ);
    }
}

// ---- fused FFN: out = h + LN(silu(h@W1+b1)@W2 + b2) ----
// Both weights LDS-resident; t1 stays in registers (in-wave shuffle transpose).
__global__ __launch_bounds__(256) void ffn_fused(const float* __restrict__ h,
                                                 const short* __restrict__ Wt1,
                                                 const short* __restrict__ Wt2,
                                                 const float* __restrict__ b1,
                                                 const float* __restrict__ b2,
                                                 const float* __restrict__ g,
                                                 const float* __restrict__ be,
                                                 float* __restrict__ out, int M) {
    __shared__ __attribute__((aligned(16))) short Bs1[128 * 136];
    __shared__ __attribute__((aligned(16))) short Bs2[128 * 136];
    {
        const short8* wp1 = (const short8*)Wt1;
        const short8* wp2 = (const short8*)Wt2;
        const int tid = threadIdx.x;
#pragma unroll
        for (int it = 0; it < 8; ++it) {
            int i = it * 256 + tid;
            int n = i >> 4, kg = i & 15;
            *(short8*)(&Bs1[n * 136 + kg * 8]) = wp1[i];
            *(short8*)(&Bs2[n * 136 + kg * 8]) = wp2[i];
        }
        __syncthreads();
    }
    const int tid = threadIdx.x;
    const int wv = tid >> 6, lane = tid & 63;
    const int m = lane & 15, quad = lane >> 4;
    const int qh = quad >> 1;                 // t-select for transpose
    const int srcA = ((quad & 1) << 5) + m;   // lane holding chunk q_s
    const int ntiles = (M + 63) >> 6;

    for (int tile = blockIdx.x; tile < ntiles; tile += gridDim.x) {
        const int row = tile * 64 + wv * 16 + m;
        const bool valid = row < M;
        const float* hp = h + (size_t)row * D128;

        // A-frags of h (fp32 -> bf16)
        short8 af[4];
#pragma unroll
        for (int kk = 0; kk < 4; ++kk) {
            float4 u0v = make_float4(0.f, 0.f, 0.f, 0.f), u1v = u0v;
            if (valid) {
                u0v = *(const float4*)(hp + kk * 32 + quad * 8);
                u1v = *(const float4*)(hp + kk * 32 + quad * 8 + 4);
            }
            short8 sfr;
            sfr[0] = f2bf(u0v.x); sfr[1] = f2bf(u0v.y); sfr[2] = f2bf(u0v.z); sfr[3] = f2bf(u0v.w);
            sfr[4] = f2bf(u1v.x); sfr[5] = f2bf(u1v.y); sfr[6] = f2bf(u1v.z); sfr[7] = f2bf(u1v.w);
            af[kk] = sfr;
        }

        // GEMM1
        floatx4 acc[8];
#pragma unroll
        for (int t = 0; t < 8; ++t) acc[t] = (floatx4){0.f, 0.f, 0.f, 0.f};
#pragma unroll
        for (int kk = 0; kk < 4; ++kk) {
            const int kq = kk * 32 + quad * 8;
#pragma unroll
            for (int t = 0; t < 8; ++t) {
                short8 bf = *(const short8*)(&Bs1[(t * 16 + m) * 136 + kq]);
                acc[t] = __builtin_amdgcn_mfma_f32_16x16x32_bf16(bf, af[kk], acc[t], 0, 0, 0);
            }
        }

        // bias + silu + pack to bf16 chunk dwords (chunk t: cols t*16+quad*4 ..+3)
        unsigned u0[8], u1[8];
#pragma unroll
        for (int t = 0; t < 8; ++t) {
            const int c = t * 16 + quad * 4;
            floatx4 bv = *(const floatx4*)(b1 + c);
            float w0 = acc[t][0] + bv[0], w1 = acc[t][1] + bv[1];
            float w2 = acc[t][2] + bv[2], w3 = acc[t][3] + bv[3];
            w0 = w0 / (1.f + __expf(-w0));
            w1 = w1 / (1.f + __expf(-w1));
            w2 = w2 / (1.f + __expf(-w2));
            w3 = w3 / (1.f + __expf(-w3));
            u0[t] = (unsigned)(unsigned short)f2bf(w0) | ((unsigned)(unsigned short)f2bf(w1) << 16);
            u1[t] = (unsigned)(unsigned short)f2bf(w2) | ((unsigned)(unsigned short)f2bf(w3) << 16);
        }

        // in-wave transpose: af2[kk] = t1[row m][kk*32 + quad*8 .. +7]
        short8 af2[4];
#pragma unroll
        for (int kk = 0; kk < 4; ++kk) {
            const int tA = 2 * kk, tB = 2 * kk + 1;
            unsigned a0 = __shfl(u0[tA], srcA),      c0 = __shfl(u0[tB], srcA);
            unsigned a1 = __shfl(u1[tA], srcA),      c1 = __shfl(u1[tB], srcA);
            unsigned a2 = __shfl(u0[tA], srcA + 16), c2 = __shfl(u0[tB], srcA + 16);
            unsigned a3 = __shfl(u1[tA], srcA + 16), c3 = __shfl(u1[tB], srcA + 16);
            union { unsigned u[4]; short8 s; } cv;
            cv.u[0] = qh ? c0 : a0;
            cv.u[1] = qh ? c1 : a1;
            cv.u[2] = qh ? c2 : a2;
            cv.u[3] = qh ? c3 : a3;
            af2[kk] = cv.s;
        }

        // GEMM2
        floatx4 acc2[8];
#pragma unroll
        for (int t = 0; t < 8; ++t) acc2[t] = (floatx4){0.f, 0.f, 0.f, 0.f};
#pragma unroll
        for (int kk = 0; kk < 4; ++kk) {
            const int kq = kk * 32 + quad * 8;
#pragma unroll
            for (int t = 0; t < 8; ++t) {
                short8 bf = *(const short8*)(&Bs2[(t * 16 + m) * 136 + kq]);
                acc2[t] = __builtin_amdgcn_mfma_f32_16x16x32_bf16(bf, af2[kk], acc2[t], 0, 0, 0);
            }
        }

        // LN epilogue (row spread over 4 quad-lanes; reduce via xor 16,32)
        float vals[8][4];
        float sum = 0.f;
#pragma unroll
        for (int t = 0; t < 8; ++t) {
            const int c = t * 16 + quad * 4;
            floatx4 bv = *(const floatx4*)(b2 + c);
#pragma unroll
            for (int r = 0; r < 4; ++r) {
                float vv = acc2[t][r] + bv[r];
                vals[t][r] = vv;
                sum += vv;
            }
        }
        sum += __shfl_xor(sum, 16);
        sum += __shfl_xor(sum, 32);
        float mu = sum * (1.f / 128.f);
        float vs = 0.f;
#pragma unroll
        for (int t = 0; t < 8; ++t)
#pragma unroll
            for (int r = 0; r < 4; ++r) {
                float d = vals[t][r] - mu;
                vals[t][r] = d;
                vs += d * d;
            }
        vs += __shfl_xor(vs, 16);
        vs += __shfl_xor(vs, 32);
        float rs = rsqrtf(vs * (1.f / 128.f) + 1e-5f);

        if (valid) {
            float* op = out + (size_t)row * D128;
#pragma unroll
            for (int t = 0; t < 8; ++t) {
                const int c = t * 16 + quad * 4;
                floatx4 hv = *(const floatx4*)(hp + c);
                floatx4 gv = *(const floatx4*)(g + c);
                floatx4 bb = *(const floatx4*)(be + c);
                floatx4 o;
#pragma unroll
                for (int r = 0; r < 4; ++r) o[r] = hv[r] + vals[t][r] * rs * gv[r] + bb[r];
                *(floatx4*)(op + c) = o;
            }
        }
    }
}

// ---- CSR build ----
__global__ void hist_kernel(const int* __restrict__ ei, int* __restrict__ deg, int E) {
    int i = blockIdx.x * 256 + threadIdx.x;
    if (i < E) atomicAdd(&deg[ei[(size_t)E + i]], 1);
}

__global__ __launch_bounds__(256) void scan_a(const int* __restrict__ deg,
                                              int* __restrict__ rowstart,
                                              int* __restrict__ partials, int N) {
    __shared__ int lds[256];
    int base = blockIdx.x * 1024;
    int t = threadIdx.x;
    int v[4];
    int s = 0;
#pragma unroll
    for (int j = 0; j < 4; ++j) {
        int i = base + t * 4 + j;
        v[j] = (i < N) ? deg[i] : 0;
        s += v[j];
    }
    lds[t] = s;
    __syncthreads();
    int val = s;
    for (int off = 1; off < 256; off <<= 1) {
        int other = (t >= off) ? lds[t - off] : 0;
        __syncthreads();
        val += other;
        lds[t] = val;
        __syncthreads();
    }
    int excl = val - s;
#pragma unroll
    for (int j = 0; j < 4; ++j) {
        int i = base + t * 4 + j;
        if (i < N) rowstart[i] = excl;
        excl += v[j];
    }
    if (t == 255) partials[blockIdx.x] = val;
}

__global__ __launch_bounds__(256) void scan_b(int* __restrict__ partials, int n) {
    __shared__ int lds[256];
    int t = threadIdx.x;
    int s = (t < n) ? partials[t] : 0;
    lds[t] = s;
    __syncthreads();
    int val = s;
    for (int off = 1; off < 256; off <<= 1) {
        int other = (t >= off) ? lds[t - off] : 0;
        __syncthreads();
        val += other;
        lds[t] = val;
        __syncthreads();
    }
    if (t < n) partials[t] = val - s;
}

// also seeds cursor (drops a D2D memcpy)
__global__ void scan_c(int* __restrict__ rowstart, const int* __restrict__ partials,
                       int* __restrict__ cursor, int N, int Etot) {
    int i = blockIdx.x * 256 + threadIdx.x;
    if (i < N) {
        int v = rowstart[i] + partials[i >> 10];
        rowstart[i] = v;
        cursor[i] = v;
    }
    if (i == 0) rowstart[N] = Etot;
}

// builds csrc[slot]=src and pos[edge]=slot (for CSR-ordered e projection)
__global__ void fill_kernel(const int* __restrict__ ei, int* __restrict__ cursor,
                            int* __restrict__ csrc, int* __restrict__ pos, int E) {
    int i = blockIdx.x * 256 + threadIdx.x;
    if (i >= E) return;
    int src = ei[i], dst = ei[(size_t)E + i];
    int slot = atomicAdd(&cursor[dst], 1);
    csrc[slot] = src;
    pos[i] = slot;
}

// ---- fused attention gather + (h = x + LN(attn + skip)) ----
// e pre-permuted to CSR order -> sequential; 4-way unroll for MLP.
__global__ __launch_bounds__(256) void attn_ln_h(const int* __restrict__ rowstart,
                                                 const int* __restrict__ csrc,
                                                 const unsigned* __restrict__ q2,
                                                 const unsigned* __restrict__ k2,
                                                 const unsigned* __restrict__ v2,
                                                 const unsigned* __restrict__ ep2,
                                                 const unsigned* __restrict__ skip2,
                                                 const float* __restrict__ x,
                                                 const float* __restrict__ g,
                                                 const float* __restrict__ b,
                                                 float* __restrict__ h, int N) {
    int t = threadIdx.x;
    int node = blockIdx.x * 4 + (t >> 6);
    if (node >= N) return;
    int l = t & 63;
    unsigned qu = q2[(size_t)node * 64 + l];
    float q0 = bflo(qu), q1 = bfhi(qu);
    int p0 = rowstart[node], p1 = rowstart[node + 1];
    float num0 = 0.f, num1 = 0.f, den = 0.f;
    int p = p0;
    for (; p + 3 < p1; p += 4) {
        int s0 = csrc[p], s1 = csrc[p + 1], s2 = csrc[p + 2], s3 = csrc[p + 3];
        unsigned ku0 = k2[(size_t)s0 * 64 + l];
        unsigned ku1 = k2[(size_t)s1 * 64 + l];
        unsigned ku2 = k2[(size_t)s2 * 64 + l];
        unsigned ku3 = k2[(size_t)s3 * 64 + l];
        unsigned eu0 = ep2[(size_t)p * 64 + l];
        unsigned eu1 = ep2[(size_t)(p + 1) * 64 + l];
        unsigned eu2 = ep2[(size_t)(p + 2) * 64 + l];
        unsigned eu3 = ep2[(size_t)(p + 3) * 64 + l];
        unsigned vu0 = v2[(size_t)s0 * 64 + l];
        unsigned vu1 = v2[(size_t)s1 * 64 + l];
        unsigned vu2 = v2[(size_t)s2 * 64 + l];
        unsigned vu3 = v2[(size_t)s3 * 64 + l];
        float pd0 = q0 * (bflo(ku0) + bflo(eu0)) + q1 * (bfhi(ku0) + bfhi(eu0));
        float pd1 = q0 * (bflo(ku1) + bflo(eu1)) + q1 * (bfhi(ku1) + bfhi(eu1));
        float pd2 = q0 * (bflo(ku2) + bflo(eu2)) + q1 * (bfhi(ku2) + bfhi(eu2));
        float pd3 = q0 * (bflo(ku3) + bflo(eu3)) + q1 * (bfhi(ku3) + bfhi(eu3));
        pd0 += __shfl_xor(pd0, 1); pd1 += __shfl_xor(pd1, 1);
        pd2 += __shfl_xor(pd2, 1); pd3 += __shfl_xor(pd3, 1);
        pd0 += __shfl_xor(pd0, 2); pd1 += __shfl_xor(pd1, 2);
        pd2 += __shfl_xor(pd2, 2); pd3 += __shfl_xor(pd3, 2);
        pd0 += __shfl_xor(pd0, 4); pd1 += __shfl_xor(pd1, 4);
        pd2 += __shfl_xor(pd2, 4); pd3 += __shfl_xor(pd3, 4);
        float ex0 = __expf(pd0 * 0.25f);
        float ex1 = __expf(pd1 * 0.25f);
        float ex2 = __expf(pd2 * 0.25f);
        float ex3 = __expf(pd3 * 0.25f);
        den += (ex0 + ex1) + (ex2 + ex3);
        num0 += ex0 * (bflo(vu0) + bflo(eu0)) + ex1 * (bflo(vu1) + bflo(eu1))
              + ex2 * (bflo(vu2) + bflo(eu2)) + ex3 * (bflo(vu3) + bflo(eu3));
        num1 += ex0 * (bfhi(vu0) + bfhi(eu0)) + ex1 * (bfhi(vu1) + bfhi(eu1))
              + ex2 * (bfhi(vu2) + bfhi(eu2)) + ex3 * (bfhi(vu3) + bfhi(eu3));
    }
    for (; p < p1; ++p) {
        int s0 = csrc[p];
        unsigned ku = k2[(size_t)s0 * 64 + l];
        unsigned eu = ep2[(size_t)p * 64 + l];
        unsigned vu = v2[(size_t)s0 * 64 + l];
        float pd = q0 * (bflo(ku) + bflo(eu)) + q1 * (bfhi(ku) + bfhi(eu));
        pd += __shfl_xor(pd, 1);
        pd += __shfl_xor(pd, 2);
        pd += __shfl_xor(pd, 4);
        float ex = __expf(pd * 0.25f);
        den += ex;
        num0 += ex * (bflo(vu) + bflo(eu));
        num1 += ex * (bfhi(vu) + bfhi(eu));
    }
    float inv = 1.f / (den + 1e-16f);
    float v0 = num0 * inv, v1 = num1 * inv;

    // h = x + LN(attnrow + skip)
    unsigned su = skip2[(size_t)node * 64 + l];
    v0 += bflo(su); v1 += bfhi(su);
    float sum = v0 + v1;
#pragma unroll
    for (int o = 32; o > 0; o >>= 1) sum += __shfl_xor(sum, o);
    float mu = sum * (1.f / 128.f);
    float d0 = v0 - mu, d1 = v1 - mu;
    float vs = d0 * d0 + d1 * d1;
#pragma unroll
    for (int o = 32; o > 0; o >>= 1) vs += __shfl_xor(vs, o);
    float rs = rsqrtf(vs * (1.f / 128.f) + 1e-5f);
    int c0 = l * 2;
    size_t base = (size_t)node * D128;
    float2 xe = *(const float2*)(x + base + c0);
    float2 o2;
    o2.x = xe.x + d0 * rs * g[c0] + b[c0];
    o2.y = xe.y + d1 * rs * g[c0 + 1] + b[c0 + 1];
    *(float2*)(h + base + c0) = o2;
}

extern "C" void kernel_launch(void* const* d_in, const int* in_sizes, int n_in,
                              void* d_out, int out_size, void* d_ws, size_t ws_size,
                              hipStream_t stream) {
    const int*   ei    = (const int*)d_in[0];
    const float* x     = (const float*)d_in[1];
    const float* ea    = (const float*)d_in[2];
    const float* Wq    = (const float*)d_in[3];
    const float* bq    = (const float*)d_in[4];
    const float* Wk    = (const float*)d_in[5];
    const float* bk    = (const float*)d_in[6];
    const float* Wv    = (const float*)d_in[7];
    const float* bv    = (const float*)d_in[8];
    const float* We    = (const float*)d_in[9];
    const float* Wsk   = (const float*)d_in[10];
    const float* bskip = (const float*)d_in[11];
    const float* W1    = (const float*)d_in[12];
    const float* b1    = (const float*)d_in[13];
    const float* W2    = (const float*)d_in[14];
    const float* b2    = (const float*)d_in[15];
    const float* g1    = (const float*)d_in[16];
    const float* be1   = (const float*)d_in[17];
    const float* g2    = (const float*)d_in[18];
    const float* be2   = (const float*)d_in[19];

    const int N = in_sizes[1] / D128;
    const int E = in_sizes[2] / D128;
    const size_t nd = (size_t)N * D128;
    const size_t ed = (size_t)E * D128;

    char* p = (char*)d_ws;
    auto alloc = [&](size_t bytes) {
        char* r = p;
        p += (bytes + 255) & ~(size_t)255;
        return (void*)r;
    };
    short* qb       = (short*)alloc(nd * 2);
    short* kb       = (short*)alloc(nd * 2);
    short* vb       = (short*)alloc(nd * 2);
    short* sb       = (short*)alloc(nd * 2);   // skip
    short* ebuf     = (short*)alloc(ed * 2);   // CSR-permuted e projection
    float* h        = (float*)alloc(nd * 4);
    short* wt       = (short*)alloc(7 * 16384 * 2);
    int*   deg      = (int*)alloc((size_t)N * 4);
    int*   rowstart = (int*)alloc(((size_t)N + 1) * 4);
    int*   partials = (int*)alloc(512 * 4);
    int*   cursor   = (int*)alloc((size_t)N * 4);
    int*   csrc     = (int*)alloc((size_t)E * 4);
    int*   pos      = (int*)alloc((size_t)E * 4);

    const int tilesN = (N + 63) / 64;
    const int tilesE = (E + 63) / 64;
    const int nbE = tilesE < 1536 ? tilesE : 1536;
    const int nbQ = tilesN < 256 ? tilesN : 256;
    const int gxF = tilesN < 1024 ? tilesN : 1024;
    const int nchunks = (N + 1023) / 1024;

    wprep_kernel<<<7, 256, 0, stream>>>(Wq, Wk, Wv, We, Wsk, W1, W2, wt);

    // CSR build (by dst)
    hipMemsetAsync(deg, 0, (size_t)N * 4, stream);
    hist_kernel<<<(E + 255) / 256, 256, 0, stream>>>(ei, deg, E);
    scan_a<<<nchunks, 256, 0, stream>>>(deg, rowstart, partials, N);
    scan_b<<<1, 256, 0, stream>>>(partials, nchunks);
    scan_c<<<(N + 255) / 256, 256, 0, stream>>>(rowstart, partials, cursor, N, E);
    fill_kernel<<<(E + 255) / 256, 256, 0, stream>>>(ei, cursor, csrc, pos, E);

    // all projections in one dispatch (edge proj scattered to CSR order)
    proj_all<<<nbE + 4 * nbQ, 256, 0, stream>>>(x, ea, wt, bq, bk, bv, bskip,
                                                qb, kb, vb, sb, ebuf, pos,
                                                N, E, nbE, nbQ);

    // fused attention gather + LN-h (atomic-free)
    attn_ln_h<<<(N + 3) / 4, 256, 0, stream>>>(rowstart, csrc, (const unsigned*)qb,
                                               (const unsigned*)kb, (const unsigned*)vb,
                                               (const unsigned*)ebuf, (const unsigned*)sb,
                                               x, g1, be1, h, N);

    // fused FFN (GEMM1 + silu + GEMM2 + LN + residual), t1 never leaves registers
    ffn_fused<<<gxF, 256, 0, stream>>>(h, wt + 5 * 16384, wt + 6 * 16384,
                                       b1, b2, g2, be2, (float*)d_out, N);
}